// Round 1
// baseline (25923.337 us; speedup 1.0000x reference)
//
#include <hip/hip_runtime.h>
#include <math.h>

namespace {
constexpr int T = 512, B = 64, D = 512, H = 512;
constexpr int LDSROW = D + H + 4;  // 1028: +4 pad breaks stride-1024 bank pileup
}

__global__ __launch_bounds__(256) void zero_state(float* p, int n) {
  int i = blockIdx.x * 256 + threadIdx.x;
  if (i < n) p[i] = 0.f;
}

// One time-step for BOTH directions.
// grid = 256 blocks: d(2) x jtile(32, 16 j each) x btile(4, 16 b each)
// block = 256 threads: thread (j_sub, b_sub) owns output (b, j), computes
// all 4 gates (K=1024 dot: x-part 512 + h-part 512), then the cell update.
__global__ __launch_bounds__(256) void lstm_step(
    const float* __restrict__ x, const float* __restrict__ mask,
    const float* __restrict__ WihF, const float* __restrict__ WhhF,
    const float* __restrict__ bihF, const float* __restrict__ bhhF,
    const float* __restrict__ WihR, const float* __restrict__ WhhR,
    const float* __restrict__ bihR, const float* __restrict__ bhhR,
    const float* __restrict__ hPrev, float* __restrict__ hNext,
    float* __restrict__ cSt, float* __restrict__ out, int s)
{
  const int bx = blockIdx.x;
  const int d  = bx >> 7;          // 0 fwd, 1 rev
  const int jb = (bx >> 2) & 31;
  const int bb = bx & 3;
  const int j0 = jb * 16, b0 = bb * 16;
  const int t  = d ? (T - 1 - s) : s;

  const float* Wih = d ? WihR : WihF;
  const float* Whh = d ? WhhR : WhhF;
  const float* bih = d ? bihR : bihF;
  const float* bhh = d ? bhhR : bhhF;
  const float* hp  = hPrev + (size_t)d * B * H;
  float* hn        = hNext + (size_t)d * B * H;
  float* cp        = cSt   + (size_t)d * B * H;

  __shared__ float xh[16][LDSROW];

  const int tid = threadIdx.x;
  // stage x[t][b0:b0+16][:] and h_prev[b0:b0+16][:] into LDS (float4, coalesced)
  for (int i = tid; i < 16 * (D / 4); i += 256) {
    int row = i >> 7;          // 128 float4 per 512-f32 row
    int k4  = i & 127;
    *(float4*)&xh[row][k4 * 4] =
        *(const float4*)(x + ((size_t)t * B + b0 + row) * D + (size_t)k4 * 4);
    *(float4*)&xh[row][D + k4 * 4] =
        *(const float4*)(hp + (size_t)(b0 + row) * H + (size_t)k4 * 4);
  }
  __syncthreads();

  const int j_sub = tid >> 4, b_sub = tid & 15;
  const int j  = j0 + j_sub;
  const int bg = b0 + b_sub;

  float a0 = bih[j]         + bhh[j];          // i gate
  float a1 = bih[H + j]     + bhh[H + j];      // f gate
  float a2 = bih[2 * H + j] + bhh[2 * H + j];  // g gate
  float a3 = bih[3 * H + j] + bhh[3 * H + j];  // o gate

  const float* wi0 = Wih + (size_t)j * D;
  const float* wi1 = Wih + (size_t)(H + j) * D;
  const float* wi2 = Wih + (size_t)(2 * H + j) * D;
  const float* wi3 = Wih + (size_t)(3 * H + j) * D;

  #pragma unroll 8
  for (int k4 = 0; k4 < D / 4; ++k4) {
    float4 xv = *(const float4*)&xh[b_sub][k4 * 4];
    float4 w0 = *(const float4*)(wi0 + (size_t)k4 * 4);
    float4 w1 = *(const float4*)(wi1 + (size_t)k4 * 4);
    float4 w2 = *(const float4*)(wi2 + (size_t)k4 * 4);
    float4 w3 = *(const float4*)(wi3 + (size_t)k4 * 4);
    a0 += xv.x * w0.x + xv.y * w0.y + xv.z * w0.z + xv.w * w0.w;
    a1 += xv.x * w1.x + xv.y * w1.y + xv.z * w1.z + xv.w * w1.w;
    a2 += xv.x * w2.x + xv.y * w2.y + xv.z * w2.z + xv.w * w2.w;
    a3 += xv.x * w3.x + xv.y * w3.y + xv.z * w3.z + xv.w * w3.w;
  }

  const float* wh0 = Whh + (size_t)j * H;
  const float* wh1 = Whh + (size_t)(H + j) * H;
  const float* wh2 = Whh + (size_t)(2 * H + j) * H;
  const float* wh3 = Whh + (size_t)(3 * H + j) * H;

  #pragma unroll 8
  for (int k4 = 0; k4 < H / 4; ++k4) {
    float4 hv = *(const float4*)&xh[b_sub][D + k4 * 4];
    float4 w0 = *(const float4*)(wh0 + (size_t)k4 * 4);
    float4 w1 = *(const float4*)(wh1 + (size_t)k4 * 4);
    float4 w2 = *(const float4*)(wh2 + (size_t)k4 * 4);
    float4 w3 = *(const float4*)(wh3 + (size_t)k4 * 4);
    a0 += hv.x * w0.x + hv.y * w0.y + hv.z * w0.z + hv.w * w0.w;
    a1 += hv.x * w1.x + hv.y * w1.y + hv.z * w1.z + hv.w * w1.w;
    a2 += hv.x * w2.x + hv.y * w2.y + hv.z * w2.z + hv.w * w2.w;
    a3 += hv.x * w3.x + hv.y * w3.y + hv.z * w3.z + hv.w * w3.w;
  }

  float ig = 1.f / (1.f + expf(-a0));
  float fg = 1.f / (1.f + expf(-a1));
  float gg = tanhf(a2);
  float og = 1.f / (1.f + expf(-a3));

  float cOld = cp[(size_t)bg * H + j];
  float hOld = xh[b_sub][D + j];   // staged h_prev row holds all 512 cols

  float cNew = fg * cOld + ig * gg;
  float hNew = og * tanhf(cNew);

  float m  = mask[(size_t)t * B + bg];
  float hm = hNew * m + hOld * (1.f - m);
  float cm = cNew * m + cOld * (1.f - m);

  cp[(size_t)bg * H + j] = cm;
  hn[(size_t)bg * H + j] = hm;
  out[((size_t)t * B + bg) * (2 * H) + (size_t)d * H + j] = hm;
}

extern "C" void kernel_launch(void* const* d_in, const int* in_sizes, int n_in,
                              void* d_out, int out_size, void* d_ws, size_t ws_size,
                              hipStream_t stream) {
  const float* x    = (const float*)d_in[0];
  const float* mask = (const float*)d_in[1];
  const float* WihF = (const float*)d_in[2];
  const float* WhhF = (const float*)d_in[3];
  const float* bihF = (const float*)d_in[4];
  const float* bhhF = (const float*)d_in[5];
  const float* WihR = (const float*)d_in[6];
  const float* WhhR = (const float*)d_in[7];
  const float* bihR = (const float*)d_in[8];
  const float* bhhR = (const float*)d_in[9];
  float* out = (float*)d_out;

  float* ws   = (float*)d_ws;
  float* hbuf = ws;                          // 2 bufs x 2 dirs x B x H
  float* cbuf = ws + 2 * 2 * B * H;          // 2 dirs x B x H
  int nz = 2 * 2 * B * H + 2 * B * H;        // zero h (both bufs) + c
  zero_state<<<(nz + 255) / 256, 256, 0, stream>>>(ws, nz);

  for (int s = 0; s < T; ++s) {
    const float* hp = hbuf + (size_t)(s & 1) * 2 * B * H;
    float*       hn = hbuf + (size_t)((s & 1) ^ 1) * 2 * B * H;
    lstm_step<<<256, 256, 0, stream>>>(x, mask, WihF, WhhF, bihF, bhhF,
                                       WihR, WhhR, bihR, bhhR,
                                       hp, hn, cbuf, out, s);
  }
}

// Round 2
// 22618.578 us; speedup vs baseline: 1.1461x; 1.1461x over previous
//
#include <hip/hip_runtime.h>
#include <hip/hip_cooperative_groups.h>
#include <math.h>

namespace cg = cooperative_groups;

namespace {
constexpr int T = 512, B = 64, D = 512, H = 512;
constexpr int WROW = 1028;          // 1024 k + 4 pad (breaks stride-4096 bank pileup)
constexpr int CHK  = 128;           // k-chunk staged per double-buffer half
constexpr int XROW = 132;           // CHK + 4 pad
constexpr int WLDS = 16 * WROW;     // 16448 floats (4 gates x 4 j rows)
constexpr int XLDS = 2 * B * XROW;  // 16896 floats (double-buffered xh chunks)
constexpr int PROW = 36;            // 32 partials (4g x 8kq) + 4 pad
}

// Persistent bi-LSTM. grid=256 blocks (1/CU): dir(2) x jtile(128, 4 j each).
// block=512 threads (2 waves/SIMD). Weights live in LDS for the whole kernel;
// c,h state lives in finisher-thread registers; h exchanged via global dbuf
// with one grid.sync() per time-step.
__global__ __launch_bounds__(512, 2) void bilstm_persistent(
    const float* __restrict__ x, const float* __restrict__ mask,
    const float* __restrict__ WihF, const float* __restrict__ WhhF,
    const float* __restrict__ bihF, const float* __restrict__ bhhF,
    const float* __restrict__ WihR, const float* __restrict__ WhhR,
    const float* __restrict__ bihR, const float* __restrict__ bhhR,
    float* __restrict__ hbuf, float* __restrict__ out)
{
  cg::grid_group grid = cg::this_grid();
  __shared__ float smem[WLDS + XLDS];     // 133,376 B LDS
  float* const wlds = smem;
  float* const xh   = smem + WLDS;
  float* const P    = smem + WLDS;        // overlays xh; used only between steps

  const int tid = threadIdx.x;
  const int dir = (int)blockIdx.x >> 7;
  const int j0  = ((int)blockIdx.x & 127) * 4;

  const float* __restrict__ Wih = dir ? WihR : WihF;
  const float* __restrict__ Whh = dir ? WhhR : WhhF;
  const float* __restrict__ bih = dir ? bihR : bihF;
  const float* __restrict__ bhh = dir ? bhhR : bhhF;

  // ---- weights -> LDS, once. row = g*4+jj holds [Wih_row | Whh_row] (1024 k)
  for (int idx = tid; idx < 16 * 256; idx += 512) {
    const int row = idx >> 8, f4 = idx & 255;
    const int g = row >> 2, jj = row & 3;
    const int k = f4 * 4;
    const float* src = (k < D)
        ? Wih + (size_t)(g * H + j0 + jj) * D + k
        : Whh + (size_t)(g * H + j0 + jj) * H + (k - D);
    *(float4*)&wlds[row * WROW + k] = *(const float4*)src;
  }

  // ---- finisher threads (tid<256) own output (b=tid&63, jj=tid>>6):
  // bias sums + persistent c,h registers; zero step-0 h buffer (own columns).
  const int fb = tid & 63, fjj = tid >> 6;
  float bs0 = 0.f, bs1 = 0.f, bs2 = 0.f, bs3 = 0.f, cReg = 0.f, hReg = 0.f;
  if (tid < 256) {
    bs0 = bih[0 * H + j0 + fjj] + bhh[0 * H + j0 + fjj];
    bs1 = bih[1 * H + j0 + fjj] + bhh[1 * H + j0 + fjj];
    bs2 = bih[2 * H + j0 + fjj] + bhh[2 * H + j0 + fjj];
    bs3 = bih[3 * H + j0 + fjj] + bhh[3 * H + j0 + fjj];
    hbuf[((size_t)dir * B + fb) * H + j0 + fjj] = 0.f;   // buf0
  }

  // ---- compute-role decomposition: thread = (bq 16, jjc 4, kq 8)
  // owns 4 b (b=bq+16i), 1 j, 4 gates, k-slice kq*16..+15 of each 128-chunk.
  const int bq  = tid & 15;
  const int jjc = (tid >> 4) & 3;
  const int kq  = tid >> 6;

  // stage-role: thread covers (b = tid>>5 + 16r, f4 = tid&31), r=0..3
  float4 gx0, gx1, gx2, gx3;
  const int sb = tid >> 5, sf4 = tid & 31;

  auto issue_chunk = [&](int c, int s) {
    const int t = dir ? (T - 1 - s) : s;
    const float* src = (c < 4)
        ? x + (size_t)t * B * D + c * CHK
        : hbuf + ((size_t)((s & 1) * 2 + dir) * B) * H + (c * CHK - D);
    src += (size_t)sb * 512 + sf4 * 4;
    gx0 = *(const float4*)(src);
    gx1 = *(const float4*)(src + 16 * 512);
    gx2 = *(const float4*)(src + 32 * 512);
    gx3 = *(const float4*)(src + 48 * 512);
  };
  auto write_chunk = [&](int c) {
    float* dst = xh + (c & 1) * (B * XROW) + sb * XROW + sf4 * 4;
    *(float4*)(dst)             = gx0;
    *(float4*)(dst + 16 * XROW) = gx1;
    *(float4*)(dst + 32 * XROW) = gx2;
    *(float4*)(dst + 48 * XROW) = gx3;
  };

  issue_chunk(0, 0);
  grid.sync();   // step-0 h zeros + weights visible

  for (int s = 0; s < T; ++s) {
    float acc[4][4];
    #pragma unroll
    for (int i = 0; i < 4; ++i)
      #pragma unroll
      for (int g = 0; g < 4; ++g) acc[i][g] = 0.f;

    #pragma unroll 2
    for (int c = 0; c < 8; ++c) {
      __syncthreads();                       // buf (c&1) free (compute c-2 done)
      write_chunk(c);                        // vmcnt wait auto-inserted
      if (c < 7) issue_chunk(c + 1, s);      // overlap next loads with compute
      __syncthreads();                       // chunk c visible
      // ---- compute chunk c: 4 iters x (8 ds_read_b128 + 64 fmac)
      const float* wb = wlds + jjc * WROW + c * CHK + kq * 16;
      const float* xb = xh + (c & 1) * (B * XROW) + kq * 16;
      #pragma unroll
      for (int k4 = 0; k4 < 4; ++k4) {
        const int ko = k4 * 4;
        float4 w0 = *(const float4*)(wb + 0 * 4 * WROW + ko);
        float4 w1 = *(const float4*)(wb + 1 * 4 * WROW + ko);
        float4 w2 = *(const float4*)(wb + 2 * 4 * WROW + ko);
        float4 w3 = *(const float4*)(wb + 3 * 4 * WROW + ko);
        #pragma unroll
        for (int i = 0; i < 4; ++i) {
          float4 hv = *(const float4*)(xb + (bq + 16 * i) * XROW + ko);
          acc[i][0] += hv.x * w0.x + hv.y * w0.y + hv.z * w0.z + hv.w * w0.w;
          acc[i][1] += hv.x * w1.x + hv.y * w1.y + hv.z * w1.z + hv.w * w1.w;
          acc[i][2] += hv.x * w2.x + hv.y * w2.y + hv.z * w2.z + hv.w * w2.w;
          acc[i][3] += hv.x * w3.x + hv.y * w3.y + hv.z * w3.z + hv.w * w3.w;
        }
      }
    }

    __syncthreads();                         // all computes done; xh reusable as P
    #pragma unroll
    for (int i = 0; i < 4; ++i)
      #pragma unroll
      for (int g = 0; g < 4; ++g)
        P[((bq + 16 * i) * 4 + jjc) * PROW + g * 8 + kq] = acc[i][g];
    __syncthreads();

    if (tid < 256) {
      const float* pr = P + (fb * 4 + fjj) * PROW;
      float s0 = bs0, s1 = bs1, s2 = bs2, s3 = bs3;
      #pragma unroll
      for (int g4 = 0; g4 < 2; ++g4) {       // 8 float4 reads: 4 gates x 8 kq
        float4 a0 = *(const float4*)(pr + 0 * 8 + g4 * 4);
        float4 a1 = *(const float4*)(pr + 1 * 8 + g4 * 4);
        float4 a2 = *(const float4*)(pr + 2 * 8 + g4 * 4);
        float4 a3 = *(const float4*)(pr + 3 * 8 + g4 * 4);
        s0 += a0.x + a0.y + a0.z + a0.w;
        s1 += a1.x + a1.y + a1.z + a1.w;
        s2 += a2.x + a2.y + a2.z + a2.w;
        s3 += a3.x + a3.y + a3.z + a3.w;
      }
      const int t = dir ? (T - 1 - s) : s;
      const float ig = 1.f / (1.f + expf(-s0));
      const float fg = 1.f / (1.f + expf(-s1));
      const float gg = tanhf(s2);
      const float og = 1.f / (1.f + expf(-s3));
      const float cNew = fg * cReg + ig * gg;
      const float hNew = og * tanhf(cNew);
      const float m = mask[(size_t)t * B + fb];
      hReg = hNew * m + hReg * (1.f - m);
      cReg = cNew * m + cReg * (1.f - m);
      hbuf[((size_t)(((s + 1) & 1) * 2 + dir) * B + fb) * H + j0 + fjj] = hReg;
      out[((size_t)t * B + fb) * (2 * H) + (size_t)dir * H + j0 + fjj] = hReg;
    }
    if (s + 1 < T) issue_chunk(0, s + 1);    // x prefetch hides under grid.sync
    grid.sync();
  }
}

extern "C" void kernel_launch(void* const* d_in, const int* in_sizes, int n_in,
                              void* d_out, int out_size, void* d_ws, size_t ws_size,
                              hipStream_t stream) {
  const float* x    = (const float*)d_in[0];
  const float* mask = (const float*)d_in[1];
  const float* WihF = (const float*)d_in[2];
  const float* WhhF = (const float*)d_in[3];
  const float* bihF = (const float*)d_in[4];
  const float* bhhF = (const float*)d_in[5];
  const float* WihR = (const float*)d_in[6];
  const float* WhhR = (const float*)d_in[7];
  const float* bihR = (const float*)d_in[8];
  const float* bhhR = (const float*)d_in[9];
  float* hbuf = (float*)d_ws;               // 2 bufs x 2 dirs x B x H = 512 KB
  float* outp = (float*)d_out;

  void* args[] = {(void*)&x, (void*)&mask,
                  (void*)&WihF, (void*)&WhhF, (void*)&bihF, (void*)&bhhF,
                  (void*)&WihR, (void*)&WhhR, (void*)&bihR, (void*)&bhhR,
                  (void*)&hbuf, (void*)&outp};
  hipLaunchCooperativeKernel((const void*)bilstm_persistent,
                             dim3(256), dim3(512), args, 0, stream);
}